// Round 3
// baseline (1284.241 us; speedup 1.0000x reference)
//
#include <hip/hip_runtime.h>
#include <hip/hip_bf16.h>
#include <cstdint>

#define D_MODEL 1024
#define D_FF    4096
#define NEXP    8
#define TOPK    2
#define TOKENS  8192                 // B*S
#define NPAIR   (TOKENS * TOPK)      // 16384
#define NPAD    (NPAIR + 128)        // 16512 (slack so tile staging stays in-bounds)

typedef __bf16 bf16x8 __attribute__((ext_vector_type(8)));
typedef float  f32x4  __attribute__((ext_vector_type(4)));

__device__ __forceinline__ unsigned short f2bf(float f) {
    unsigned int u = __float_as_uint(f);
    unsigned int r = (u + 0x7FFFu + ((u >> 16) & 1u)) >> 16;
    return (unsigned short)r;
}

__device__ __forceinline__ void lds_load16(void* lds, const void* g) {
    __builtin_amdgcn_global_load_lds(
        (const __attribute__((address_space(1))) void*)g,
        (__attribute__((address_space(3))) void*)lds, 16, 0, 0);
}

// tanh-form GELU: one v_exp_f32; saturates correctly at +/-inf; |err vs erf-gelu| < 3e-3
__device__ __forceinline__ float fast_gelu(float v) {
    float y2 = 1.5957691216f * (v + 0.044715f * v * v * v);   // 2*sqrt(2/pi)*(v+...)
    float t = 1.0f - 2.0f / (__expf(y2) + 1.0f);              // tanh(y2/2*2)=tanh(y)
    return 0.5f * v * (1.0f + t);
}

// ---------------- gating: logits -> softmax -> top2 -> renorm ----------------
__global__ __launch_bounds__(64) void gate_kernel(
        const float* __restrict__ x, const float* __restrict__ gw,
        int* __restrict__ tok_e, float* __restrict__ tok_w, int* __restrict__ cnt)
{
    const int t = blockIdx.x;
    const int lane = threadIdx.x;
    const float* xr = x + (size_t)t * D_MODEL;
    float xv[16];
#pragma unroll
    for (int i = 0; i < 16; ++i) xv[i] = xr[lane + 64 * i];
    float lg[NEXP];
#pragma unroll
    for (int e = 0; e < NEXP; ++e) {
        const float* g = gw + e * D_MODEL;
        float s = 0.f;
#pragma unroll
        for (int i = 0; i < 16; ++i) s += xv[i] * g[lane + 64 * i];
        for (int off = 32; off; off >>= 1) s += __shfl_down(s, off);
        lg[e] = s;
    }
    if (lane == 0) {
        float m = lg[0];
#pragma unroll
        for (int e = 1; e < NEXP; ++e) m = fmaxf(m, lg[e]);
        float ex[NEXP], S = 0.f;
#pragma unroll
        for (int e = 0; e < NEXP; ++e) { ex[e] = expf(lg[e] - m); S += ex[e]; }
        int i0 = 0; float p0 = ex[0];
#pragma unroll
        for (int e = 1; e < NEXP; ++e) if (ex[e] > p0) { p0 = ex[e]; i0 = e; }
        int i1 = -1; float p1 = -1.f;
#pragma unroll
        for (int e = 0; e < NEXP; ++e) if (e != i0 && ex[e] > p1) { p1 = ex[e]; i1 = e; }
        float q0 = p0 / S, q1 = p1 / S;
        float denom = q0 + q1 + 1e-9f;
        tok_e[2 * t] = i0; tok_e[2 * t + 1] = i1;
        tok_w[2 * t] = q0 / denom; tok_w[2 * t + 1] = q1 / denom;
        atomicAdd(&cnt[i0], 1); atomicAdd(&cnt[i1], 1);
    }
}

__global__ void offsets_kernel(const int* __restrict__ cnt, int* __restrict__ offs,
                               int* __restrict__ fill)
{
    if (threadIdx.x == 0 && blockIdx.x == 0) {
        int s = 0;
        for (int e = 0; e < NEXP; ++e) { offs[e] = s; fill[e] = s; s += cnt[e]; }
        offs[NEXP] = s;
    }
}

__global__ __launch_bounds__(256) void scatter_kernel(
        const int* __restrict__ tok_e, const float* __restrict__ tok_w,
        int* __restrict__ fill, int* __restrict__ pair_tok, float* __restrict__ pair_w)
{
    int t = blockIdx.x * 256 + threadIdx.x;
    if (t >= TOKENS) return;
#pragma unroll
    for (int k = 0; k < TOPK; ++k) {
        int e = tok_e[2 * t + k];
        int pos = atomicAdd(&fill[e], 1);
        pair_tok[pos] = t;
        pair_w[pos] = tok_w[2 * t + k];
    }
}

// ---------------- gather x rows per pair, convert to bf16 ----------------
__global__ __launch_bounds__(256) void gather_cvt(
        const float* __restrict__ x, const int* __restrict__ pair_tok,
        unsigned short* __restrict__ Xg)
{
    int p = blockIdx.x;
    int tok = pair_tok[p];
    const float4* src = (const float4*)(x + (size_t)tok * D_MODEL);
    ushort4* dst = (ushort4*)(Xg + (size_t)p * D_MODEL);
    float4 v = src[threadIdx.x];
    ushort4 o;
    o.x = f2bf(v.x); o.y = f2bf(v.y); o.z = f2bf(v.z); o.w = f2bf(v.w);
    dst[threadIdx.x] = o;
}

// ---------------- transpose + convert weights: fp32 [E][R][C] -> bf16 [E][C][R] ----
__global__ __launch_bounds__(256) void transpose_cvt(
        const float* __restrict__ in, unsigned short* __restrict__ out, int R, int C)
{
    __shared__ float tile[32][33];
    const int e = blockIdx.z;
    const int r0 = blockIdx.y * 32, c0 = blockIdx.x * 32;
    const float* src = in + (size_t)e * R * C;
    unsigned short* dst = out + (size_t)e * R * C;
    const int tx = threadIdx.x & 31, ty = threadIdx.x >> 5;   // ty 0..7
#pragma unroll
    for (int i = 0; i < 32; i += 8)
        tile[ty + i][tx] = src[(size_t)(r0 + ty + i) * C + (c0 + tx)];
    __syncthreads();
#pragma unroll
    for (int i = 0; i < 32; i += 8)
        dst[(size_t)(c0 + ty + i) * R + (r0 + tx)] = f2bf(tile[tx][ty + i]);
}

// ---------------- GEMM1: H[p][f] = gelu(Xg[p] . w1t[e][f] + b1[e][f]) ----------------
// Grid: x = m-tile (XCD-affinity: blocks sharing an m-tile differ by gridDim.x=64
// in linear id, 64 % 8 == 0 -> same XCD -> A-tile L2 reuse), y = n-tile, z = expert.
__global__ __launch_bounds__(256) void gemm1_kernel(
        const unsigned short* __restrict__ Xg, const unsigned short* __restrict__ w1t,
        const float* __restrict__ b1, const int* __restrict__ offs,
        unsigned short* __restrict__ H)
{
    const int e = blockIdx.z;
    const int seg1 = offs[e + 1];
    const int row0 = offs[e] + blockIdx.x * 128;
    if (row0 >= seg1) return;
    const int n0 = blockIdx.y * 128;

    __shared__ __align__(16) unsigned short As[128 * 32];
    __shared__ __align__(16) unsigned short Bs[128 * 32];

    const int t = threadIdx.x;
    const int ra = t >> 2;
    const int ca = (t & 3) * 8;
    const unsigned short* ag = Xg + (size_t)(row0 + ra) * D_MODEL + ca;
    const unsigned short* bg = w1t + (size_t)e * D_FF * D_MODEL
                                   + (size_t)(n0 + ra) * D_MODEL + ca;

    const int wave = t >> 6, lane = t & 63;
    const int wm = wave & 1, wn = wave >> 1;
    const int lm = lane & 15, quad = lane >> 4;

    f32x4 c[4][4] = {};

    for (int kt = 0; kt < D_MODEL; kt += 32) {
        lds_load16(As + t * 8, ag + kt);
        lds_load16(As + 2048 + t * 8, ag + 64 * D_MODEL + kt);
        lds_load16(Bs + t * 8, bg + kt);
        lds_load16(Bs + 2048 + t * 8, bg + 64 * D_MODEL + kt);
        __syncthreads();
        bf16x8 a[4], b[4];
#pragma unroll
        for (int i = 0; i < 4; ++i) {
            a[i] = *(const bf16x8*)&As[(wm * 64 + i * 16 + lm) * 32 + quad * 8];
            b[i] = *(const bf16x8*)&Bs[(wn * 64 + i * 16 + lm) * 32 + quad * 8];
        }
#pragma unroll
        for (int i = 0; i < 4; ++i)
#pragma unroll
            for (int j = 0; j < 4; ++j)
                c[i][j] = __builtin_amdgcn_mfma_f32_16x16x32_bf16(a[i], b[j], c[i][j], 0, 0, 0);
        __syncthreads();
    }

    float b1v[4];
#pragma unroll
    for (int j = 0; j < 4; ++j)
        b1v[j] = b1[e * D_FF + n0 + wn * 64 + j * 16 + lm];
#pragma unroll
    for (int i = 0; i < 4; ++i) {
#pragma unroll
        for (int r = 0; r < 4; ++r) {
            int gm = row0 + wm * 64 + i * 16 + quad * 4 + r;
            if (gm < seg1) {
#pragma unroll
                for (int j = 0; j < 4; ++j) {
                    int gn = n0 + wn * 64 + j * 16 + lm;
                    float v = c[i][j][r] + b1v[j];
                    H[(size_t)gm * D_FF + gn] = f2bf(fast_gelu(v));
                }
            }
        }
    }
}

// ---------------- GEMM2: out[tok] += w_p * (H[p] . w2t[e][d] + b2[e][d]) ----------------
// Grid: x = m-tile, y = n-tile (8), z = expert. Same XCD-affinity rationale.
__global__ __launch_bounds__(256) void gemm2_kernel(
        const unsigned short* __restrict__ H, const unsigned short* __restrict__ w2t,
        const float* __restrict__ b2, const int* __restrict__ offs,
        const int* __restrict__ pair_tok, const float* __restrict__ pair_w,
        float* __restrict__ out)
{
    const int e = blockIdx.z;
    const int seg1 = offs[e + 1];
    const int row0 = offs[e] + blockIdx.x * 128;
    if (row0 >= seg1) return;
    const int n0 = blockIdx.y * 128;

    __shared__ __align__(16) unsigned short As[128 * 32];
    __shared__ __align__(16) unsigned short Bs[128 * 32];

    const int t = threadIdx.x;
    const int ra = t >> 2;
    const int ca = (t & 3) * 8;
    const unsigned short* ag = H + (size_t)(row0 + ra) * D_FF + ca;
    const unsigned short* bg = w2t + (size_t)e * D_MODEL * D_FF
                                   + (size_t)(n0 + ra) * D_FF + ca;

    const int wave = t >> 6, lane = t & 63;
    const int wm = wave & 1, wn = wave >> 1;
    const int lm = lane & 15, quad = lane >> 4;

    f32x4 c[4][4] = {};

    for (int kt = 0; kt < D_FF; kt += 32) {
        lds_load16(As + t * 8, ag + kt);
        lds_load16(As + 2048 + t * 8, ag + 64 * D_FF + kt);
        lds_load16(Bs + t * 8, bg + kt);
        lds_load16(Bs + 2048 + t * 8, bg + 64 * D_FF + kt);
        __syncthreads();
        bf16x8 a[4], b[4];
#pragma unroll
        for (int i = 0; i < 4; ++i) {
            a[i] = *(const bf16x8*)&As[(wm * 64 + i * 16 + lm) * 32 + quad * 8];
            b[i] = *(const bf16x8*)&Bs[(wn * 64 + i * 16 + lm) * 32 + quad * 8];
        }
#pragma unroll
        for (int i = 0; i < 4; ++i)
#pragma unroll
            for (int j = 0; j < 4; ++j)
                c[i][j] = __builtin_amdgcn_mfma_f32_16x16x32_bf16(a[i], b[j], c[i][j], 0, 0, 0);
        __syncthreads();
    }

    float b2v[4];
#pragma unroll
    for (int j = 0; j < 4; ++j)
        b2v[j] = b2[e * D_MODEL + n0 + wn * 64 + j * 16 + lm];
#pragma unroll
    for (int i = 0; i < 4; ++i) {
#pragma unroll
        for (int r = 0; r < 4; ++r) {
            int gm = row0 + wm * 64 + i * 16 + quad * 4 + r;
            if (gm < seg1) {
                int tok = pair_tok[gm];
                float wgt = pair_w[gm];
#pragma unroll
                for (int j = 0; j < 4; ++j) {
                    int gn = n0 + wn * 64 + j * 16 + lm;
                    float v = (c[i][j][r] + b2v[j]) * wgt;
                    atomicAdd(&out[(size_t)tok * D_MODEL + gn], v);
                }
            }
        }
    }
}

// ---------------- launcher ----------------
// Workspace: single 64 MiB WT buffer reused for w1^T then w2^T (stream-serialized).
// Total ~225.5 MiB; staying under input total (~288 MiB) — round-1 overflow lesson.
extern "C" void kernel_launch(void* const* d_in, const int* in_sizes, int n_in,
                              void* d_out, int out_size, void* d_ws, size_t ws_size,
                              hipStream_t stream)
{
    const float* x      = (const float*)d_in[0];
    const float* gate_w = (const float*)d_in[1];
    const float* w1     = (const float*)d_in[2];
    const float* b1     = (const float*)d_in[3];
    const float* w2     = (const float*)d_in[4];
    const float* b2     = (const float*)d_in[5];
    float* out = (float*)d_out;

    char* ws = (char*)d_ws;
    const size_t WT_OFF   = 0;                                              // 64 MiB (shared w1t/w2t)
    const size_t XG_OFF   = WT_OFF + (size_t)NEXP * D_FF * D_MODEL * 2;
    const size_t H_OFF    = XG_OFF + (size_t)NPAD * D_MODEL * 2;
    const size_t PTOK_OFF = H_OFF + (size_t)NPAD * D_FF * 2;
    const size_t PW_OFF   = PTOK_OFF + (size_t)NPAD * 4;
    const size_t TOKE_OFF = PW_OFF + (size_t)NPAD * 4;
    const size_t TOKW_OFF = TOKE_OFF + (size_t)NPAIR * 4;
    const size_t CNT_OFF  = TOKW_OFF + (size_t)NPAIR * 4;

    unsigned short* wt  = (unsigned short*)(ws + WT_OFF);
    unsigned short* Xg  = (unsigned short*)(ws + XG_OFF);
    unsigned short* H   = (unsigned short*)(ws + H_OFF);
    int*   pair_tok = (int*)(ws + PTOK_OFF);
    float* pair_w   = (float*)(ws + PW_OFF);
    int*   tok_e    = (int*)(ws + TOKE_OFF);
    float* tok_w    = (float*)(ws + TOKW_OFF);
    int*   cnt      = (int*)(ws + CNT_OFF);   // 8 ints
    int*   fill     = cnt + 8;                // 8 ints
    int*   offs     = cnt + 16;               // 9 ints

    hipMemsetAsync(cnt, 0, 64, stream);
    hipMemsetAsync(out, 0, (size_t)out_size * sizeof(float), stream);

    gate_kernel<<<TOKENS, 64, 0, stream>>>(x, gate_w, tok_e, tok_w, cnt);
    offsets_kernel<<<1, 64, 0, stream>>>(cnt, offs, fill);
    scatter_kernel<<<TOKENS / 256, 256, 0, stream>>>(tok_e, tok_w, fill, pair_tok, pair_w);
    gather_cvt<<<NPAIR, 256, 0, stream>>>(x, pair_tok, Xg);

    // w1^T into WT, GEMM1, then w2^T into the SAME WT buffer, GEMM2.
    transpose_cvt<<<dim3(D_FF / 32, D_MODEL / 32, NEXP), 256, 0, stream>>>(w1, wt, D_MODEL, D_FF);
    gemm1_kernel<<<dim3(TOKENS / 128, D_FF / 128, NEXP), 256, 0, stream>>>(Xg, wt, b1, offs, H);
    transpose_cvt<<<dim3(D_MODEL / 32, D_FF / 32, NEXP), 256, 0, stream>>>(w2, wt, D_FF, D_MODEL);
    gemm2_kernel<<<dim3(TOKENS / 128, D_MODEL / 128, NEXP), 256, 0, stream>>>(H, wt, b2, offs, pair_tok, pair_w, out);
}

// Round 4
// 1079.551 us; speedup vs baseline: 1.1896x; 1.1896x over previous
//
#include <hip/hip_runtime.h>
#include <hip/hip_bf16.h>
#include <cstdint>

#define D_MODEL 1024
#define D_FF    4096
#define NEXP    8
#define TOPK    2
#define TOKENS  8192                 // B*S
#define NPAIR   (TOKENS * TOPK)      // 16384
#define NPAD    (NPAIR + 128)        // 16512 (slack so tile staging stays in-bounds)

typedef __bf16 bf16x8 __attribute__((ext_vector_type(8)));
typedef float  f32x4  __attribute__((ext_vector_type(4)));

__device__ __forceinline__ unsigned short f2bf(float f) {
    unsigned int u = __float_as_uint(f);
    unsigned int r = (u + 0x7FFFu + ((u >> 16) & 1u)) >> 16;
    return (unsigned short)r;
}

__device__ __forceinline__ void lds_load16(void* lds, const void* g) {
    __builtin_amdgcn_global_load_lds(
        (const __attribute__((address_space(1))) void*)g,
        (__attribute__((address_space(3))) void*)lds, 16, 0, 0);
}

// tanh-form GELU: one v_exp_f32; saturates correctly at +/-inf; |err vs erf-gelu| < 3e-3
__device__ __forceinline__ float fast_gelu(float v) {
    float y2 = 1.5957691216f * (v + 0.044715f * v * v * v);   // 2*sqrt(2/pi)*(v+...)
    float t = 1.0f - 2.0f / (__expf(y2) + 1.0f);
    return 0.5f * v * (1.0f + t);
}

// ---------------- gating: logits -> softmax -> top2 -> renorm ----------------
__global__ __launch_bounds__(64) void gate_kernel(
        const float* __restrict__ x, const float* __restrict__ gw,
        int* __restrict__ tok_e, float* __restrict__ tok_w, int* __restrict__ cnt)
{
    const int t = blockIdx.x;
    const int lane = threadIdx.x;
    const float* xr = x + (size_t)t * D_MODEL;
    float xv[16];
#pragma unroll
    for (int i = 0; i < 16; ++i) xv[i] = xr[lane + 64 * i];
    float lg[NEXP];
#pragma unroll
    for (int e = 0; e < NEXP; ++e) {
        const float* g = gw + e * D_MODEL;
        float s = 0.f;
#pragma unroll
        for (int i = 0; i < 16; ++i) s += xv[i] * g[lane + 64 * i];
        for (int off = 32; off; off >>= 1) s += __shfl_down(s, off);
        lg[e] = s;
    }
    if (lane == 0) {
        float m = lg[0];
#pragma unroll
        for (int e = 1; e < NEXP; ++e) m = fmaxf(m, lg[e]);
        float ex[NEXP], S = 0.f;
#pragma unroll
        for (int e = 0; e < NEXP; ++e) { ex[e] = expf(lg[e] - m); S += ex[e]; }
        int i0 = 0; float p0 = ex[0];
#pragma unroll
        for (int e = 1; e < NEXP; ++e) if (ex[e] > p0) { p0 = ex[e]; i0 = e; }
        int i1 = -1; float p1 = -1.f;
#pragma unroll
        for (int e = 0; e < NEXP; ++e) if (e != i0 && ex[e] > p1) { p1 = ex[e]; i1 = e; }
        float q0 = p0 / S, q1 = p1 / S;
        float denom = q0 + q1 + 1e-9f;
        tok_e[2 * t] = i0; tok_e[2 * t + 1] = i1;
        tok_w[2 * t] = q0 / denom; tok_w[2 * t + 1] = q1 / denom;
        atomicAdd(&cnt[i0], 1); atomicAdd(&cnt[i1], 1);
    }
}

__global__ void offsets_kernel(const int* __restrict__ cnt, int* __restrict__ offs,
                               int* __restrict__ fill)
{
    if (threadIdx.x == 0 && blockIdx.x == 0) {
        int s = 0;
        for (int e = 0; e < NEXP; ++e) { offs[e] = s; fill[e] = s; s += cnt[e]; }
        offs[NEXP] = s;
    }
}

__global__ __launch_bounds__(256) void scatter_kernel(
        const int* __restrict__ tok_e, const float* __restrict__ tok_w,
        int* __restrict__ fill, int* __restrict__ pair_tok, float* __restrict__ pair_w)
{
    int t = blockIdx.x * 256 + threadIdx.x;
    if (t >= TOKENS) return;
#pragma unroll
    for (int k = 0; k < TOPK; ++k) {
        int e = tok_e[2 * t + k];
        int pos = atomicAdd(&fill[e], 1);
        pair_tok[pos] = t;
        pair_w[pos] = tok_w[2 * t + k];
    }
}

// ---------------- gather x rows per pair, convert to bf16 ----------------
__global__ __launch_bounds__(256) void gather_cvt(
        const float* __restrict__ x, const int* __restrict__ pair_tok,
        unsigned short* __restrict__ Xg)
{
    int p = blockIdx.x;
    int tok = pair_tok[p];
    const float4* src = (const float4*)(x + (size_t)tok * D_MODEL);
    ushort4* dst = (ushort4*)(Xg + (size_t)p * D_MODEL);
    float4 v = src[threadIdx.x];
    ushort4 o;
    o.x = f2bf(v.x); o.y = f2bf(v.y); o.z = f2bf(v.z); o.w = f2bf(v.w);
    dst[threadIdx.x] = o;
}

// ---------------- transpose + convert weights: fp32 [E][R][C] -> bf16 [E][C][R] ----
__global__ __launch_bounds__(256) void transpose_cvt(
        const float* __restrict__ in, unsigned short* __restrict__ out, int R, int C)
{
    __shared__ float tile[32][33];
    const int e = blockIdx.z;
    const int r0 = blockIdx.y * 32, c0 = blockIdx.x * 32;
    const float* src = in + (size_t)e * R * C;
    unsigned short* dst = out + (size_t)e * R * C;
    const int tx = threadIdx.x & 31, ty = threadIdx.x >> 5;   // ty 0..7
#pragma unroll
    for (int i = 0; i < 32; i += 8)
        tile[ty + i][tx] = src[(size_t)(r0 + ty + i) * C + (c0 + tx)];
    __syncthreads();
#pragma unroll
    for (int i = 0; i < 32; i += 8)
        dst[(size_t)(c0 + ty + i) * R + (r0 + tx)] = f2bf(tile[tx][ty + i]);
}

// ---------------- GEMM1: H[p][f] = gelu(Xg[p] . w1t[e][f] + b1[e][f]) ----------------
// r2 orientation: x = n-tile (fastest -> B-tile pinned per XCD-L2), y = m-tile.
__global__ __launch_bounds__(256, 2) void gemm1_kernel(
        const unsigned short* __restrict__ Xg, const unsigned short* __restrict__ w1t,
        const float* __restrict__ b1, const int* __restrict__ offs,
        unsigned short* __restrict__ H)
{
    const int e = blockIdx.z;
    const int seg1 = offs[e + 1];
    const int row0 = offs[e] + blockIdx.y * 128;
    if (row0 >= seg1) return;
    const int n0 = blockIdx.x * 128;

    __shared__ __align__(16) unsigned short As[128 * 32];
    __shared__ __align__(16) unsigned short Bs[128 * 32];

    const int t = threadIdx.x;
    const int ra = t >> 2;
    const int ca = (t & 3) * 8;
    const unsigned short* ag = Xg + (size_t)(row0 + ra) * D_MODEL + ca;
    const unsigned short* bg = w1t + (size_t)e * D_FF * D_MODEL
                                   + (size_t)(n0 + ra) * D_MODEL + ca;

    const int wave = t >> 6, lane = t & 63;
    const int wm = wave & 1, wn = wave >> 1;
    const int lm = lane & 15, quad = lane >> 4;

    f32x4 c[4][4] = {};

    for (int kt = 0; kt < D_MODEL; kt += 32) {
        lds_load16(As + t * 8, ag + kt);
        lds_load16(As + 2048 + t * 8, ag + 64 * D_MODEL + kt);
        lds_load16(Bs + t * 8, bg + kt);
        lds_load16(Bs + 2048 + t * 8, bg + 64 * D_MODEL + kt);
        __syncthreads();
        bf16x8 a[4], b[4];
#pragma unroll
        for (int i = 0; i < 4; ++i) {
            a[i] = *(const bf16x8*)&As[(wm * 64 + i * 16 + lm) * 32 + quad * 8];
            b[i] = *(const bf16x8*)&Bs[(wn * 64 + i * 16 + lm) * 32 + quad * 8];
        }
#pragma unroll
        for (int i = 0; i < 4; ++i)
#pragma unroll
            for (int j = 0; j < 4; ++j)
                c[i][j] = __builtin_amdgcn_mfma_f32_16x16x32_bf16(a[i], b[j], c[i][j], 0, 0, 0);
        __syncthreads();
    }

    float b1v[4];
#pragma unroll
    for (int j = 0; j < 4; ++j)
        b1v[j] = b1[e * D_FF + n0 + wn * 64 + j * 16 + lm];
#pragma unroll
    for (int i = 0; i < 4; ++i) {
#pragma unroll
        for (int r = 0; r < 4; ++r) {
            int gm = row0 + wm * 64 + i * 16 + quad * 4 + r;
            if (gm < seg1) {
#pragma unroll
                for (int j = 0; j < 4; ++j) {
                    int gn = n0 + wn * 64 + j * 16 + lm;
                    float v = c[i][j][r] + b1v[j];
                    H[(size_t)gm * D_FF + gn] = f2bf(fast_gelu(v));
                }
            }
        }
    }
}

// ---------------- GEMM2: out[tok] += w_p * (H[p] . w2t[e][d] + b2[e][d]) ----------------
// 128x256 tile (M x N): halves H re-reads (4 n-blocks per m-tile instead of 8).
// x = n-tile (4), y = m-tile (64), z = expert.
__global__ __launch_bounds__(256, 2) void gemm2_kernel(
        const unsigned short* __restrict__ H, const unsigned short* __restrict__ w2t,
        const float* __restrict__ b2, const int* __restrict__ offs,
        const int* __restrict__ pair_tok, const float* __restrict__ pair_w,
        float* __restrict__ out)
{
    const int e = blockIdx.z;
    const int seg1 = offs[e + 1];
    const int row0 = offs[e] + blockIdx.y * 128;
    if (row0 >= seg1) return;
    const int n0 = blockIdx.x * 256;

    __shared__ __align__(16) unsigned short As[128 * 32];   //  8 KB
    __shared__ __align__(16) unsigned short Bs[256 * 32];   // 16 KB

    const int t = threadIdx.x;
    const int ra = t >> 2;
    const int ca = (t & 3) * 8;
    const unsigned short* ag = H + (size_t)(row0 + ra) * D_FF + ca;
    const unsigned short* bg = w2t + (size_t)e * D_MODEL * D_FF
                                   + (size_t)(n0 + ra) * D_FF + ca;

    const int wave = t >> 6, lane = t & 63;
    const int wm = wave & 1, wn = wave >> 1;     // wave covers 64 rows x 128 cols
    const int lm = lane & 15, quad = lane >> 4;

    f32x4 c[4][8] = {};

    for (int kt = 0; kt < D_FF; kt += 32) {
        lds_load16(As + t * 8, ag + kt);
        lds_load16(As + 2048 + t * 8, ag + (size_t)64 * D_FF + kt);
        lds_load16(Bs + t * 8, bg + kt);
        lds_load16(Bs + 2048 + t * 8, bg + (size_t)64 * D_FF + kt);
        lds_load16(Bs + 4096 + t * 8, bg + (size_t)128 * D_FF + kt);
        lds_load16(Bs + 6144 + t * 8, bg + (size_t)192 * D_FF + kt);
        __syncthreads();
        bf16x8 a[4], b[8];
#pragma unroll
        for (int i = 0; i < 4; ++i)
            a[i] = *(const bf16x8*)&As[(wm * 64 + i * 16 + lm) * 32 + quad * 8];
#pragma unroll
        for (int j = 0; j < 8; ++j)
            b[j] = *(const bf16x8*)&Bs[(wn * 128 + j * 16 + lm) * 32 + quad * 8];
#pragma unroll
        for (int i = 0; i < 4; ++i)
#pragma unroll
            for (int j = 0; j < 8; ++j)
                c[i][j] = __builtin_amdgcn_mfma_f32_16x16x32_bf16(a[i], b[j], c[i][j], 0, 0, 0);
        __syncthreads();
    }

    float b2v[8];
#pragma unroll
    for (int j = 0; j < 8; ++j)
        b2v[j] = b2[e * D_MODEL + n0 + wn * 128 + j * 16 + lm];
#pragma unroll
    for (int i = 0; i < 4; ++i) {
#pragma unroll
        for (int r = 0; r < 4; ++r) {
            int gm = row0 + wm * 64 + i * 16 + quad * 4 + r;
            if (gm < seg1) {
                int tok = pair_tok[gm];
                float wgt = pair_w[gm];
#pragma unroll
                for (int j = 0; j < 8; ++j) {
                    int gn = n0 + wn * 128 + j * 16 + lm;
                    float v = (c[i][j][r] + b2v[j]) * wgt;
                    atomicAdd(&out[(size_t)tok * D_MODEL + gn], v);
                }
            }
        }
    }
}

// ---------------- launcher ----------------
// Workspace: single 64 MiB WT buffer reused for w1^T then w2^T (stream-serialized).
// Total ~225.5 MiB; staying under input total (~288 MiB) — round-1 overflow lesson.
extern "C" void kernel_launch(void* const* d_in, const int* in_sizes, int n_in,
                              void* d_out, int out_size, void* d_ws, size_t ws_size,
                              hipStream_t stream)
{
    const float* x      = (const float*)d_in[0];
    const float* gate_w = (const float*)d_in[1];
    const float* w1     = (const float*)d_in[2];
    const float* b1     = (const float*)d_in[3];
    const float* w2     = (const float*)d_in[4];
    const float* b2     = (const float*)d_in[5];
    float* out = (float*)d_out;

    char* ws = (char*)d_ws;
    const size_t WT_OFF   = 0;                                              // 64 MiB (shared w1t/w2t)
    const size_t XG_OFF   = WT_OFF + (size_t)NEXP * D_FF * D_MODEL * 2;
    const size_t H_OFF    = XG_OFF + (size_t)NPAD * D_MODEL * 2;
    const size_t PTOK_OFF = H_OFF + (size_t)NPAD * D_FF * 2;
    const size_t PW_OFF   = PTOK_OFF + (size_t)NPAD * 4;
    const size_t TOKE_OFF = PW_OFF + (size_t)NPAD * 4;
    const size_t TOKW_OFF = TOKE_OFF + (size_t)NPAIR * 4;
    const size_t CNT_OFF  = TOKW_OFF + (size_t)NPAIR * 4;

    unsigned short* wt  = (unsigned short*)(ws + WT_OFF);
    unsigned short* Xg  = (unsigned short*)(ws + XG_OFF);
    unsigned short* H   = (unsigned short*)(ws + H_OFF);
    int*   pair_tok = (int*)(ws + PTOK_OFF);
    float* pair_w   = (float*)(ws + PW_OFF);
    int*   tok_e    = (int*)(ws + TOKE_OFF);
    float* tok_w    = (float*)(ws + TOKW_OFF);
    int*   cnt      = (int*)(ws + CNT_OFF);   // 8 ints
    int*   fill     = cnt + 8;                // 8 ints
    int*   offs     = cnt + 16;               // 9 ints

    hipMemsetAsync(cnt, 0, 64, stream);
    hipMemsetAsync(out, 0, (size_t)out_size * sizeof(float), stream);

    gate_kernel<<<TOKENS, 64, 0, stream>>>(x, gate_w, tok_e, tok_w, cnt);
    offsets_kernel<<<1, 64, 0, stream>>>(cnt, offs, fill);
    scatter_kernel<<<TOKENS / 256, 256, 0, stream>>>(tok_e, tok_w, fill, pair_tok, pair_w);
    gather_cvt<<<NPAIR, 256, 0, stream>>>(x, pair_tok, Xg);

    // w1^T into WT, GEMM1, then w2^T into the SAME WT buffer, GEMM2.
    transpose_cvt<<<dim3(D_FF / 32, D_MODEL / 32, NEXP), 256, 0, stream>>>(w1, wt, D_MODEL, D_FF);
    gemm1_kernel<<<dim3(D_FF / 128, TOKENS / 128, NEXP), 256, 0, stream>>>(Xg, wt, b1, offs, H);
    transpose_cvt<<<dim3(D_MODEL / 32, D_FF / 32, NEXP), 256, 0, stream>>>(w2, wt, D_FF, D_MODEL);
    gemm2_kernel<<<dim3(D_MODEL / 256, TOKENS / 128, NEXP), 256, 0, stream>>>(H, wt, b2, offs, pair_tok, pair_w, out);
}